// Round 11
// baseline (1822.028 us; speedup 1.0000x reference)
//
#include <hip/hip_runtime.h>
#include <cstdint>
#include <cstddef>

#define B_ 16
#define S_ 512
#define D_ 512
#define H_ 8
#define DK_ 64
#define NL_ 6
#define DFF_ 2048

typedef float f32x4 __attribute__((ext_vector_type(4)));
typedef __bf16 bf16x8 __attribute__((ext_vector_type(8)));
typedef unsigned short u16x8 __attribute__((ext_vector_type(8)));

__device__ __forceinline__ unsigned short f2bf(float f) {
  unsigned u = __builtin_bit_cast(unsigned, f);
  unsigned r = (u + 0x7FFFu + ((u >> 16) & 1u)) >> 16;  // RNE
  return (unsigned short)r;
}
__device__ __forceinline__ float bf2f(unsigned short v) {
  unsigned u = ((unsigned)v) << 16;
  return __builtin_bit_cast(float, u);
}

// async global->LDS, 16B per lane (m97 staging lever)
__device__ __forceinline__ void gl_lds16(const unsigned short* g, unsigned short* l) {
  __builtin_amdgcn_global_load_lds(
      (const __attribute__((address_space(1))) unsigned int*)g,
      (__attribute__((address_space(3))) unsigned int*)l, 16, 0, 0);
}

// ---------------- positional encoding add: xo = x + pe2d ----------------
__global__ __launch_bounds__(256) void pe_add_kernel(const float* __restrict__ x,
                                                     const float* __restrict__ coords,
                                                     const float* __restrict__ cls_pe,
                                                     float* __restrict__ xo) {
  int idx = blockIdx.x * 256 + threadIdx.x;
  int d = idx & (D_ - 1);
  int s = (idx >> 9) & (S_ - 1);
  float pe;
  if (s == 0) {
    pe = cls_pe[d];
  } else {
    float c = coords[(s - 1) * 2 + (d >= 256 ? 1 : 0)];
    int dd = d & 255;
    int t = dd >> 1;
    float ang = c * expf((float)t * -0.07195578415606394f);
    pe = (dd & 1) ? cosf(ang) : sinf(ang);
  }
  xo[idx] = x[idx] + pe;
}

// ---------------- rel-pos bias table, bf16, fragment-permuted ----------------
// layout [h][i][t(4)][lr(16)][n(8)]: attn thread (lr) reads bf16x8 per (i, t)
__global__ __launch_bounds__(256) void bias_kernel(const float* __restrict__ coords,
                                                   const float* __restrict__ emb,
                                                   unsigned short* __restrict__ bias) {
  int idx = blockIdx.x * 256 + threadIdx.x;  // i*S + j
  int j = idx & (S_ - 1), i = idx >> 9;
  unsigned short v[H_];
  if (i == 0 || j == 0) {
#pragma unroll
    for (int h = 0; h < H_; h++) v[h] = 0;
  } else {
    float dx = coords[(i - 1) * 2] - coords[(j - 1) * 2];
    float dy = coords[(i - 1) * 2 + 1] - coords[(j - 1) * 2 + 1];
    float dist = sqrtf(dx * dx + dy * dy);
    float t = fminf(dist / 10.0f, 1.0f) * 31.0f;
    int bkt = (int)t;
#pragma unroll
    for (int h = 0; h < H_; h++) v[h] = f2bf(emb[bkt * H_ + h]);
  }
  int t = j >> 7, w = j & 127, plr = w & 15, pn = w >> 4;
#pragma unroll
  for (int h = 0; h < H_; h++)
    bias[(((size_t)h * S_ + i) * 4 + t) * 128 + plr * 8 + pn] = v[h];
}

// ---------------- transpose + fp32->bf16: dst[c][r] = src[r][c] ----------------
__global__ __launch_bounds__(256) void transpose_cvt(const float* __restrict__ src,
                                                     unsigned short* __restrict__ dst,
                                                     int R, int C) {
  src += (size_t)blockIdx.z * R * C;
  dst += (size_t)blockIdx.z * R * C;
  __shared__ float tile[32][33];
  int tx = threadIdx.x & 31, ty = threadIdx.x >> 5;  // 32 x 8
  int c0 = blockIdx.x * 32, r0 = blockIdx.y * 32;
#pragma unroll
  for (int i = 0; i < 32; i += 8)
    tile[ty + i][tx] = src[(size_t)(r0 + ty + i) * C + c0 + tx];
  __syncthreads();
#pragma unroll
  for (int i = 0; i < 32; i += 8)
    dst[(size_t)(c0 + ty + i) * R + r0 + tx] = f2bf(tile[tx][ty + i]);
}

// ---------------- LayerNorm: one wave per row of 512 ----------------
template <int OUTMODE>  // 0: bf16 out; 1: fp32 out (in-place ok)
__global__ __launch_bounds__(256) void ln_kernel(const float* __restrict__ x,
                                                 const float* __restrict__ g,
                                                 const float* __restrict__ be,
                                                 void* __restrict__ out) {
  int wid = threadIdx.x >> 6, l = threadIdx.x & 63;
  size_t row = (size_t)blockIdx.x * 4 + wid;
  const float4* xr = reinterpret_cast<const float4*>(x + row * D_);
  float4 a = xr[l * 2], c = xr[l * 2 + 1];
  float s = a.x + a.y + a.z + a.w + c.x + c.y + c.z + c.w;
  float sq = a.x * a.x + a.y * a.y + a.z * a.z + a.w * a.w +
             c.x * c.x + c.y * c.y + c.z * c.z + c.w * c.w;
#pragma unroll
  for (int m = 1; m < 64; m <<= 1) {
    s += __shfl_xor(s, m);
    sq += __shfl_xor(sq, m);
  }
  float mean = s * (1.0f / D_);
  float var = sq * (1.0f / D_) - mean * mean;
  float rstd = rsqrtf(var + 1e-5f);
  const float4* gp = reinterpret_cast<const float4*>(g);
  const float4* bp = reinterpret_cast<const float4*>(be);
  float4 g0 = gp[l * 2], g1 = gp[l * 2 + 1];
  float4 b0 = bp[l * 2], b1 = bp[l * 2 + 1];
  float y[8];
  y[0] = (a.x - mean) * rstd * g0.x + b0.x;
  y[1] = (a.y - mean) * rstd * g0.y + b0.y;
  y[2] = (a.z - mean) * rstd * g0.z + b0.z;
  y[3] = (a.w - mean) * rstd * g0.w + b0.w;
  y[4] = (c.x - mean) * rstd * g1.x + b1.x;
  y[5] = (c.y - mean) * rstd * g1.y + b1.y;
  y[6] = (c.z - mean) * rstd * g1.z + b1.z;
  y[7] = (c.w - mean) * rstd * g1.w + b1.w;
  if (OUTMODE == 0) {
    u16x8 o;
#pragma unroll
    for (int j = 0; j < 8; j++) o[j] = f2bf(y[j]);
    *reinterpret_cast<u16x8*>((unsigned short*)out + row * D_ + l * 8) = o;
  } else {
    float4 o0 = {y[0], y[1], y[2], y[3]};
    float4 o1 = {y[4], y[5], y[6], y[7]};
    float4* op = reinterpret_cast<float4*>((float*)out + row * D_ + l * 8);
    op[0] = o0;
    op[1] = o1;
  }
}

// ======== GEMM epilogue (shared) ========
template <int EPI>
__device__ __forceinline__ void gemm_epi(float v, int gr, int gc, int N,
                                         unsigned short* outb, float* resid) {
  if (EPI == 0) {
    outb[(size_t)gr * N + gc] = f2bf(v);
  } else if (EPI == 1) {
    resid[(size_t)gr * N + gc] += v;
  } else if (EPI == 2) {
    float gl = 0.5f * v * (1.0f + erff(v * 0.70710678118654752f));
    outb[(size_t)gr * N + gc] = f2bf(gl);
  } else {  // EPI 4: fused QKV split-write. outb=Qb; Kb at +4M elems, VTb at +8M
    if (gc < 512) {
      outb[(size_t)gr * 512 + gc] = f2bf(v);
    } else if (gc < 1024) {
      (outb + 4194304)[(size_t)gr * 512 + (gc - 512)] = f2bf(v);
    } else {
      int c = gc - 1024;
      int h = c >> 6, dd = c & 63, bb = gr >> 9, ss = gr & 511;
      (outb + 8388608)[((size_t)((bb * H_ + h) * DK_ + dd)) * S_ + ss] = f2bf(v);
    }
  }
}

// ---------------- GEMM 128x128, 4 waves, 3-buffer counted-vmcnt pipeline ------
// For 256-block (1 block/CU) GEMMs: no TLP exists, so remove the vmcnt(0) drain.
// Per iter: barrier(all done t-1) -> issue stage(t+2) -> s_waitcnt vmcnt(N)
// (N = 8 per in-flight stage; waits only t's loads) -> barrier -> compute(t).
// Prefetched loads stay in flight ACROSS barriers (T4, m218 mechanism).
template <int EPI>
__global__ __launch_bounds__(256) void gemm_bt3(const unsigned short* __restrict__ A,
                                                const unsigned short* __restrict__ BT,
                                                const float* __restrict__ bias,
                                                unsigned short* __restrict__ outb,
                                                float* __restrict__ resid,
                                                int M, int N, int K) {
  constexpr int BK = 64;
  __shared__ __align__(16) unsigned short As[3][128 * BK];  // 48 KB
  __shared__ __align__(16) unsigned short Bs[3][128 * BK];  // 48 KB
  int tid = threadIdx.x;
  int l = tid & 63, wid = tid >> 6;
  int wr = wid >> 1, wc = wid & 1;

  int nwg = gridDim.x * gridDim.y;
  int flat = blockIdx.y * gridDim.x + blockIdx.x;
  int cpx = nwg >> 3;
  int work = (flat & 7) * cpx + (flat >> 3);
  int bx = work % gridDim.x, by = work / gridDim.x;
  int m0 = by * 128, n0 = bx * 128;
  int lr = l & 15, lk = (l >> 4) * 8;

  f32x4 acc[4][4];
#pragma unroll
  for (int m = 0; m < 4; m++)
#pragma unroll
    for (int n = 0; n < 4; n++) acc[m][n] = f32x4{0.f, 0.f, 0.f, 0.f};

  int sr = tid >> 3;         // 0..31 (TPR=8)
  int sc8 = (tid & 7) * 8;   // 0..56
  const unsigned short* Ag = A + (size_t)(m0 + sr) * K + sc8;
  const unsigned short* Bg = BT + (size_t)(n0 + sr) * K + sc8;

  auto stage = [&](int c, int k0) {  // 8 gl_lds per thread (4 A + 4 B)
#pragma unroll
    for (int i = 0; i < 4; i++) {
      gl_lds16(Ag + (size_t)(i * 32) * K + k0, &As[c][(sr + i * 32) * BK + sc8]);
      gl_lds16(Bg + (size_t)(i * 32) * K + k0, &Bs[c][(sr + i * 32) * BK + sc8]);
    }
  };
  auto compute = [&](int c) {
#pragma unroll
    for (int ks = 0; ks < 2; ks++) {
      bf16x8 af[4], bfr[4];
#pragma unroll
      for (int m = 0; m < 4; m++)
        af[m] = *reinterpret_cast<const bf16x8*>(&As[c][(wr * 64 + m * 16 + lr) * BK + ks * 32 + lk]);
#pragma unroll
      for (int n = 0; n < 4; n++)
        bfr[n] = *reinterpret_cast<const bf16x8*>(&Bs[c][(wc * 64 + n * 16 + lr) * BK + ks * 32 + lk]);
#pragma unroll
      for (int m = 0; m < 4; m++)
#pragma unroll
        for (int n = 0; n < 4; n++)
          acc[m][n] = __builtin_amdgcn_mfma_f32_16x16x32_bf16(af[m], bfr[n], acc[m][n], 0, 0, 0);
    }
  };

  const int nt = K / BK;  // >= 8 for all uses
  stage(0, 0);
  stage(1, BK);
  int cur = 0;
  for (int t = 0; t < nt; ++t) {
    __builtin_amdgcn_s_barrier();  // all waves finished compute(t-1): safe to overwrite buf (t+2)%3
    if (t + 2 < nt) {
      stage((t + 2) % 3, (t + 2) * BK);
      asm volatile("s_waitcnt vmcnt(16)" ::: "memory");  // t's 8 loads done; t+1,t+2 in flight
    } else if (t + 1 < nt) {
      asm volatile("s_waitcnt vmcnt(8)" ::: "memory");   // t's done; t+1 in flight
    } else {
      asm volatile("s_waitcnt vmcnt(0)" ::: "memory");
    }
    __builtin_amdgcn_sched_barrier(0);
    __builtin_amdgcn_s_barrier();  // all waves' t-loads have landed
    compute(cur);
    cur = (cur + 1) % 3;
  }

#pragma unroll
  for (int m = 0; m < 4; m++) {
#pragma unroll
    for (int n = 0; n < 4; n++) {
      int gc = n0 + wc * 64 + n * 16 + lr;
      float bv = bias[gc];
#pragma unroll
      for (int rr = 0; rr < 4; rr++) {
        int gr = m0 + wr * 64 + m * 16 + (l >> 4) * 4 + rr;
        gemm_epi<EPI>(acc[m][n][rr] + bv, gr, gc, N, outb, resid);
      }
    }
  }
}

// ---------------- GEMM 256x256, 8 waves (2x4), 2-phase dbuf ----------------
template <int EPI>
__global__ __launch_bounds__(512, 2) void gemm256(const unsigned short* __restrict__ A,
                                                  const unsigned short* __restrict__ BT,
                                                  const float* __restrict__ bias,
                                                  unsigned short* __restrict__ outb,
                                                  float* __restrict__ resid,
                                                  int M, int N, int K) {
  __shared__ __align__(16) unsigned short As[2][256 * 64];
  __shared__ __align__(16) unsigned short Bs[2][256 * 64];
  int tid = threadIdx.x;
  int l = tid & 63, wid = tid >> 6;  // 8 waves
  int wr = wid >> 2, wc = wid & 3;   // 2 x 4 -> wave owns 128(M) x 64(N)

  int nwg = gridDim.x * gridDim.y;
  int flat = blockIdx.y * gridDim.x + blockIdx.x;
  int cpx = nwg >> 3;
  int work = (flat & 7) * cpx + (flat >> 3);
  int bx = work % gridDim.x, by = work / gridDim.x;
  int m0 = by * 256, n0 = bx * 256;
  int lr = l & 15, lk = (l >> 4) * 8;

  f32x4 acc[8][4];
#pragma unroll
  for (int m = 0; m < 8; m++)
#pragma unroll
    for (int n = 0; n < 4; n++) acc[m][n] = f32x4{0.f, 0.f, 0.f, 0.f};

  int sr = tid >> 3;          // 0..63
  int sc8 = (tid & 7) * 8;    // 0..56
  const unsigned short* Ag = A + (size_t)(m0 + sr) * K + sc8;
  const unsigned short* Bg = BT + (size_t)(n0 + sr) * K + sc8;

  auto stage = [&](int c, int k0) {
#pragma unroll
    for (int i = 0; i < 4; i++) {
      gl_lds16(Ag + (size_t)(i * 64) * K + k0, &As[c][(sr + i * 64) * 64 + sc8]);
      gl_lds16(Bg + (size_t)(i * 64) * K + k0, &Bs[c][(sr + i * 64) * 64 + sc8]);
    }
  };
  auto compute = [&](int c) {
#pragma unroll
    for (int ks = 0; ks < 2; ks++) {
      bf16x8 af[8], bfr[4];
#pragma unroll
      for (int m = 0; m < 8; m++)
        af[m] = *reinterpret_cast<const bf16x8*>(&As[c][(wr * 128 + m * 16 + lr) * 64 + ks * 32 + lk]);
#pragma unroll
      for (int n = 0; n < 4; n++)
        bfr[n] = *reinterpret_cast<const bf16x8*>(&Bs[c][(wc * 64 + n * 16 + lr) * 64 + ks * 32 + lk]);
#pragma unroll
      for (int m = 0; m < 8; m++)
#pragma unroll
        for (int n = 0; n < 4; n++)
          acc[m][n] = __builtin_amdgcn_mfma_f32_16x16x32_bf16(af[m], bfr[n], acc[m][n], 0, 0, 0);
    }
  };

  const int nt = K >> 6;
  stage(0, 0);
  __syncthreads();
  int cur = 0;
  for (int t = 0; t < nt; ++t) {
    if (t + 1 < nt) stage(cur ^ 1, (t + 1) * 64);
    compute(cur);
    __syncthreads();
    cur ^= 1;
  }

#pragma unroll
  for (int m = 0; m < 8; m++) {
#pragma unroll
    for (int n = 0; n < 4; n++) {
      int gc = n0 + wc * 64 + n * 16 + lr;
      float bv = bias[gc];
#pragma unroll
      for (int rr = 0; rr < 4; rr++) {
        int gr = m0 + wr * 128 + m * 16 + (l >> 4) * 4 + rr;
        gemm_epi<EPI>(acc[m][n][rr] + bv, gr, gc, N, outb, resid);
      }
    }
  }
}

// ---------------- attention: flash-style, LDS-staged K/V tiles ----------------
__global__ __launch_bounds__(256) void attn_kernel(const unsigned short* __restrict__ Q,
                                                   const unsigned short* __restrict__ K,
                                                   const unsigned short* __restrict__ VT,
                                                   const unsigned short* __restrict__ bias,
                                                   const unsigned char* __restrict__ mask,
                                                   unsigned short* __restrict__ O) {
  __shared__ __align__(16) unsigned short Ks[128 * 64];   // 16 KB [kvrow][dk] swz
  __shared__ __align__(16) unsigned short Vs[64 * 128];   // 16 KB [dk][kv] swz
  __shared__ __align__(16) unsigned short P[4][16 * 136]; // 17.4 KB wave-private
  int tid = threadIdx.x;
  int wid = tid >> 6, l = tid & 63;
  int bh = blockIdx.x;
  int b = bh >> 3, h = bh & 7;
  int q0 = blockIdx.y * 64 + wid * 16;
  int lr = l & 15;
  int lk = (l >> 4) * 8;
  int rb = (l >> 4) * 4;

  const unsigned short* qp = Q + (size_t)(b * S_ + q0 + lr) * D_ + h * DK_ + lk;
  bf16x8 aq0 = *reinterpret_cast<const bf16x8*>(qp);
  bf16x8 aq1 = *reinterpret_cast<const bf16x8*>(qp + 32);

  f32x4 ao[4];
#pragma unroll
  for (int n = 0; n < 4; n++) ao[n] = f32x4{0.f, 0.f, 0.f, 0.f};
  float m_[4] = {-3.0e38f, -3.0e38f, -3.0e38f, -3.0e38f};
  float l_[4] = {0.f, 0.f, 0.f, 0.f};

  for (int t = 0; t < 4; t++) {
    int s0 = t * 128;
    __syncthreads();
#pragma unroll
    for (int i = 0; i < 4; i++) {
      int c = (wid * 4 + i) * 64 + l;  // 0..1023
      int krow = c >> 3, kjs = c & 7, kj = kjs ^ (krow & 7);
      gl_lds16(K + (size_t)(b * S_ + s0 + krow) * D_ + h * DK_ + kj * 8, &Ks[c * 8]);
      int dk = c >> 4, vjs = c & 15, vj = vjs ^ (dk & 7);
      gl_lds16(VT + (size_t)(bh * DK_ + dk) * S_ + s0 + vj * 8, &Vs[c * 8]);
    }
    __syncthreads();

    // S-tile: 16 q-rows x 128 kv per wave
    f32x4 sc[8];
#pragma unroll
    for (int n = 0; n < 8; n++) sc[n] = f32x4{0.f, 0.f, 0.f, 0.f};
#pragma unroll
    for (int n = 0; n < 8; n++) {
      int r = n * 16 + lr;
      bf16x8 k0 = *reinterpret_cast<const bf16x8*>(&Ks[r * 64 + (((l >> 4)) ^ (r & 7)) * 8]);
      bf16x8 k1 = *reinterpret_cast<const bf16x8*>(&Ks[r * 64 + ((4 + (l >> 4)) ^ (r & 7)) * 8]);
      sc[n] = __builtin_amdgcn_mfma_f32_16x16x32_bf16(aq0, k0, sc[n], 0, 0, 0);
      sc[n] = __builtin_amdgcn_mfma_f32_16x16x32_bf16(aq1, k1, sc[n], 0, 0, 0);
    }

    // bias fragments: permuted layout [h][i][t][lr][n] -> one bf16x8 per row
    u16x8 bvv[4];
#pragma unroll
    for (int rr = 0; rr < 4; rr++)
      bvv[rr] = *reinterpret_cast<const u16x8*>(
          bias + (((size_t)h * S_ + (q0 + rb + rr)) * 4 + t) * 128 + lr * 8);

    float pmax[4] = {-3.0e38f, -3.0e38f, -3.0e38f, -3.0e38f};
#pragma unroll
    for (int n = 0; n < 8; n++) {
      int scn = n * 16 + lr;
      bool msk = mask[b * S_ + s0 + scn] != 0;
#pragma unroll
      for (int rr = 0; rr < 4; rr++) {
        float v = sc[n][rr] * 0.125f + bf2f(bvv[rr][n]);
        v = msk ? -1e9f : v;
        sc[n][rr] = v;
        pmax[rr] = fmaxf(pmax[rr], v);
      }
    }
#pragma unroll
    for (int rr = 0; rr < 4; rr++) {
#pragma unroll
      for (int mm = 1; mm < 16; mm <<= 1) pmax[rr] = fmaxf(pmax[rr], __shfl_xor(pmax[rr], mm));
    }
    float scl[4], psum[4];
#pragma unroll
    for (int rr = 0; rr < 4; rr++) {
      float mn = fmaxf(m_[rr], pmax[rr]);
      scl[rr] = __expf(m_[rr] - mn);
      m_[rr] = mn;
      psum[rr] = 0.f;
    }
#pragma unroll
    for (int n = 0; n < 8; n++) {
#pragma unroll
      for (int rr = 0; rr < 4; rr++) {
        float p = __expf(sc[n][rr] - m_[rr]);
        psum[rr] += p;
        P[wid][(rb + rr) * 136 + n * 16 + lr] = f2bf(p);
      }
    }
#pragma unroll
    for (int rr = 0; rr < 4; rr++) {
#pragma unroll
      for (int mm = 1; mm < 16; mm <<= 1) psum[rr] += __shfl_xor(psum[rr], mm);
      l_[rr] = l_[rr] * scl[rr] + psum[rr];
    }
#pragma unroll
    for (int n = 0; n < 4; n++)
#pragma unroll
      for (int rr = 0; rr < 4; rr++) ao[n][rr] *= scl[rr];

#pragma unroll
    for (int kk = 0; kk < 4; kk++) {
      bf16x8 pa = *reinterpret_cast<const bf16x8*>(&P[wid][lr * 136 + kk * 32 + lk]);
#pragma unroll
      for (int n = 0; n < 4; n++) {
        int dk = n * 16 + lr;
        bf16x8 vb = *reinterpret_cast<const bf16x8*>(&Vs[dk * 128 + ((kk * 4 + (l >> 4)) ^ (dk & 7)) * 8]);
        ao[n] = __builtin_amdgcn_mfma_f32_16x16x32_bf16(pa, vb, ao[n], 0, 0, 0);
      }
    }
  }

  float inv[4];
#pragma unroll
  for (int rr = 0; rr < 4; rr++) inv[rr] = 1.0f / l_[rr];
#pragma unroll
  for (int n = 0; n < 4; n++)
#pragma unroll
    for (int rr = 0; rr < 4; rr++)
      O[(size_t)(b * S_ + q0 + rb + rr) * D_ + h * DK_ + n * 16 + lr] = f2bf(ao[n][rr] * inv[rr]);
}

// ---------------- launch ----------------
extern "C" void kernel_launch(void* const* d_in, const int* in_sizes, int n_in,
                              void* d_out, int out_size, void* d_ws, size_t ws_size,
                              hipStream_t stream) {
  const float* x = (const float*)d_in[0];
  const float* coords = (const float*)d_in[1];
  const float* cls_pe = (const float*)d_in[2];
  const float* bias_emb = (const float*)d_in[3];
  const float* attn_w = (const float*)d_in[4];
  const float* attn_b = (const float*)d_in[5];
  const float* ff_w1 = (const float*)d_in[6];
  const float* ff_b1 = (const float*)d_in[7];
  const float* ff_w2 = (const float*)d_in[8];
  const float* ff_b2 = (const float*)d_in[9];
  const float* ln_g = (const float*)d_in[10];
  const float* ln_b = (const float*)d_in[11];
  const float* norm_g = (const float*)d_in[12];
  const float* norm_b = (const float*)d_in[13];
  const float* norm2_g = (const float*)d_in[14];
  const float* norm2_b = (const float*)d_in[15];
  const unsigned char* mask = (const unsigned char*)d_in[16];

  char* ws = (char*)d_ws;
  float* xf = (float*)(ws + 0);                                   // 16 MB
  unsigned short* biasbuf = (unsigned short*)(ws + 16777216);     // 4 MB bf16 permuted
  unsigned short* wattnT = (unsigned short*)(ws + 25165824);      // 12 MB
  unsigned short* wff1T = (unsigned short*)(ws + 37748736);       // 12 MB
  unsigned short* wff2T = (unsigned short*)(ws + 50331648);       // 12 MB
  unsigned short* lnbuf = (unsigned short*)(ws + 62914560);       // 8 MB
  unsigned short* Qb = (unsigned short*)(ws + 71303168);          // 8 MB
  unsigned short* Kb = (unsigned short*)(ws + 79691776);          // 8 MB  (= Qb + 4194304 elems)
  unsigned short* VTb = (unsigned short*)(ws + 88080384);         // 8 MB  (= Qb + 8388608 elems)
  unsigned short* Ob = (unsigned short*)(ws + 96468992);          // 8 MB
  unsigned short* H1b = Qb;  // 32 MB FF hidden aliases Q/K/VT/O (disjoint lifetimes)

  const int M = B_ * S_;

  pe_add_kernel<<<(B_ * S_ * D_) / 256, 256, 0, stream>>>(x, coords, cls_pe, xf);
  bias_kernel<<<(S_ * S_) / 256, 256, 0, stream>>>(coords, bias_emb, biasbuf);
  transpose_cvt<<<dim3(16, 16, 24), 256, 0, stream>>>(attn_w, wattnT, 512, 512);
  transpose_cvt<<<dim3(64, 16, 6), 256, 0, stream>>>(ff_w1, wff1T, 512, 2048);
  transpose_cvt<<<dim3(16, 64, 6), 256, 0, stream>>>(ff_w2, wff2T, 2048, 512);

  for (int i = 0; i < NL_; i++) {
    ln_kernel<0><<<M / 4, 256, 0, stream>>>(xf, ln_g + (i * 2 + 0) * D_, ln_b + (i * 2 + 0) * D_, lnbuf);
    // QKV: 256^2 tile, 192 blocks
    gemm256<4><<<dim3(6, 32), 512, 0, stream>>>(lnbuf, wattnT + (size_t)(i * 4 + 0) * D_ * D_,
                                                attn_b + (i * 4 + 0) * D_, Qb, nullptr, M, 1536, D_);
    attn_kernel<<<dim3(B_ * H_, 8), 256, 0, stream>>>(Qb, Kb, VTb, biasbuf, mask, Ob);
    // O-proj: 256 blocks (1/CU) -> 3-buffer counted-vmcnt pipeline
    gemm_bt3<1><<<dim3(4, 64), 256, 0, stream>>>(Ob, wattnT + (size_t)(i * 4 + 3) * D_ * D_,
                                                 attn_b + (i * 4 + 3) * D_, nullptr, xf, M, D_, D_);
    ln_kernel<0><<<M / 4, 256, 0, stream>>>(xf, ln_g + (i * 2 + 1) * D_, ln_b + (i * 2 + 1) * D_, lnbuf);
    // FF1: 256^2 tile, 256 blocks (1/CU)
    gemm256<2><<<dim3(8, 32), 512, 0, stream>>>(lnbuf, wff1T + (size_t)i * DFF_ * D_,
                                                ff_b1 + i * DFF_, H1b, nullptr, M, DFF_, D_);
    // FF2: 256 blocks (1/CU) -> 3-buffer counted-vmcnt pipeline (split-K reverted)
    gemm_bt3<1><<<dim3(4, 64), 256, 0, stream>>>(H1b, wff2T + (size_t)i * D_ * DFF_,
                                                 ff_b2 + i * D_, nullptr, xf, M, D_, DFF_);
    if (i == 2) ln_kernel<1><<<M / 4, 256, 0, stream>>>(xf, norm2_g, norm2_b, xf);
  }
  ln_kernel<1><<<M / 4, 256, 0, stream>>>(xf, norm_g, norm_b, (float*)d_out);
}

// Round 12
// 1335.415 us; speedup vs baseline: 1.3644x; 1.3644x over previous
//
#include <hip/hip_runtime.h>
#include <cstdint>
#include <cstddef>

#define B_ 16
#define S_ 512
#define D_ 512
#define H_ 8
#define DK_ 64
#define NL_ 6
#define DFF_ 2048

typedef float f32x4 __attribute__((ext_vector_type(4)));
typedef __bf16 bf16x8 __attribute__((ext_vector_type(8)));
typedef unsigned short u16x8 __attribute__((ext_vector_type(8)));

__device__ __forceinline__ unsigned short f2bf(float f) {
  unsigned u = __builtin_bit_cast(unsigned, f);
  unsigned r = (u + 0x7FFFu + ((u >> 16) & 1u)) >> 16;  // RNE
  return (unsigned short)r;
}
__device__ __forceinline__ float bf2f(unsigned short v) {
  unsigned u = ((unsigned)v) << 16;
  return __builtin_bit_cast(float, u);
}

// async global->LDS, 16B per lane (m97 staging lever)
__device__ __forceinline__ void gl_lds16(const unsigned short* g, unsigned short* l) {
  __builtin_amdgcn_global_load_lds(
      (const __attribute__((address_space(1))) unsigned int*)g,
      (__attribute__((address_space(3))) unsigned int*)l, 16, 0, 0);
}

// ---------------- positional encoding add: xo = x + pe2d ----------------
__global__ __launch_bounds__(256) void pe_add_kernel(const float* __restrict__ x,
                                                     const float* __restrict__ coords,
                                                     const float* __restrict__ cls_pe,
                                                     float* __restrict__ xo) {
  int idx = blockIdx.x * 256 + threadIdx.x;
  int d = idx & (D_ - 1);
  int s = (idx >> 9) & (S_ - 1);
  float pe;
  if (s == 0) {
    pe = cls_pe[d];
  } else {
    float c = coords[(s - 1) * 2 + (d >= 256 ? 1 : 0)];
    int dd = d & 255;
    int t = dd >> 1;
    float ang = c * expf((float)t * -0.07195578415606394f);
    pe = (dd & 1) ? cosf(ang) : sinf(ang);
  }
  xo[idx] = x[idx] + pe;
}

// ---------------- rel-pos bias table, bf16, fragment-permuted ----------------
// layout [h][i][t(4)][lr(16)][n(8)]: attn thread (lr) reads bf16x8 per (i, t)
__global__ __launch_bounds__(256) void bias_kernel(const float* __restrict__ coords,
                                                   const float* __restrict__ emb,
                                                   unsigned short* __restrict__ bias) {
  int idx = blockIdx.x * 256 + threadIdx.x;  // i*S + j
  int j = idx & (S_ - 1), i = idx >> 9;
  unsigned short v[H_];
  if (i == 0 || j == 0) {
#pragma unroll
    for (int h = 0; h < H_; h++) v[h] = 0;
  } else {
    float dx = coords[(i - 1) * 2] - coords[(j - 1) * 2];
    float dy = coords[(i - 1) * 2 + 1] - coords[(j - 1) * 2 + 1];
    float dist = sqrtf(dx * dx + dy * dy);
    float t = fminf(dist / 10.0f, 1.0f) * 31.0f;
    int bkt = (int)t;
#pragma unroll
    for (int h = 0; h < H_; h++) v[h] = f2bf(emb[bkt * H_ + h]);
  }
  int t = j >> 7, w = j & 127, plr = w & 15, pn = w >> 4;
#pragma unroll
  for (int h = 0; h < H_; h++)
    bias[(((size_t)h * S_ + i) * 4 + t) * 128 + plr * 8 + pn] = v[h];
}

// ---------------- transpose + fp32->bf16: dst[c][r] = src[r][c] ----------------
__global__ __launch_bounds__(256) void transpose_cvt(const float* __restrict__ src,
                                                     unsigned short* __restrict__ dst,
                                                     int R, int C) {
  src += (size_t)blockIdx.z * R * C;
  dst += (size_t)blockIdx.z * R * C;
  __shared__ float tile[32][33];
  int tx = threadIdx.x & 31, ty = threadIdx.x >> 5;  // 32 x 8
  int c0 = blockIdx.x * 32, r0 = blockIdx.y * 32;
#pragma unroll
  for (int i = 0; i < 32; i += 8)
    tile[ty + i][tx] = src[(size_t)(r0 + ty + i) * C + c0 + tx];
  __syncthreads();
#pragma unroll
  for (int i = 0; i < 32; i += 8)
    dst[(size_t)(c0 + ty + i) * R + r0 + tx] = f2bf(tile[tx][ty + i]);
}

// ---------------- LayerNorm: one wave per row of 512 ----------------
template <int OUTMODE>  // 0: bf16 out; 1: fp32 out (in-place ok)
__global__ __launch_bounds__(256) void ln_kernel(const float* __restrict__ x,
                                                 const float* __restrict__ g,
                                                 const float* __restrict__ be,
                                                 void* __restrict__ out) {
  int wid = threadIdx.x >> 6, l = threadIdx.x & 63;
  size_t row = (size_t)blockIdx.x * 4 + wid;
  const float4* xr = reinterpret_cast<const float4*>(x + row * D_);
  float4 a = xr[l * 2], c = xr[l * 2 + 1];
  float s = a.x + a.y + a.z + a.w + c.x + c.y + c.z + c.w;
  float sq = a.x * a.x + a.y * a.y + a.z * a.z + a.w * a.w +
             c.x * c.x + c.y * c.y + c.z * c.z + c.w * c.w;
#pragma unroll
  for (int m = 1; m < 64; m <<= 1) {
    s += __shfl_xor(s, m);
    sq += __shfl_xor(sq, m);
  }
  float mean = s * (1.0f / D_);
  float var = sq * (1.0f / D_) - mean * mean;
  float rstd = rsqrtf(var + 1e-5f);
  const float4* gp = reinterpret_cast<const float4*>(g);
  const float4* bp = reinterpret_cast<const float4*>(be);
  float4 g0 = gp[l * 2], g1 = gp[l * 2 + 1];
  float4 b0 = bp[l * 2], b1 = bp[l * 2 + 1];
  float y[8];
  y[0] = (a.x - mean) * rstd * g0.x + b0.x;
  y[1] = (a.y - mean) * rstd * g0.y + b0.y;
  y[2] = (a.z - mean) * rstd * g0.z + b0.z;
  y[3] = (a.w - mean) * rstd * g0.w + b0.w;
  y[4] = (c.x - mean) * rstd * g1.x + b1.x;
  y[5] = (c.y - mean) * rstd * g1.y + b1.y;
  y[6] = (c.z - mean) * rstd * g1.z + b1.z;
  y[7] = (c.w - mean) * rstd * g1.w + b1.w;
  if (OUTMODE == 0) {
    u16x8 o;
#pragma unroll
    for (int j = 0; j < 8; j++) o[j] = f2bf(y[j]);
    *reinterpret_cast<u16x8*>((unsigned short*)out + row * D_ + l * 8) = o;
  } else {
    float4 o0 = {y[0], y[1], y[2], y[3]};
    float4 o1 = {y[4], y[5], y[6], y[7]};
    float4* op = reinterpret_cast<float4*>((float*)out + row * D_ + l * 8);
    op[0] = o0;
    op[1] = o1;
  }
}

// ---------------- GEMM: C = A[M,K](bf16) @ BT[N,K]^T(bf16) + bias ----------------
// R7 champion structure: 128x128 tile, 4 waves (2x2), 2-phase dbuf, BK templated:
//   BK=32 (32KB LDS) for large-grid GEMMs (keeps 3-4 blocks/CU TLP)
//   BK=64 (64KB LDS) for 256-block GEMMs (1 block/CU; pipeline is the only hiding)
// T1 bijective XCD swizzle (all grids have nwg%8==0).
template <int EPI, int BK>
__global__ __launch_bounds__(256) void gemm_bt(const unsigned short* __restrict__ A,
                                               const unsigned short* __restrict__ BT,
                                               const float* __restrict__ bias,
                                               unsigned short* __restrict__ outb,
                                               float* __restrict__ resid,
                                               int M, int N, int K) {
  constexpr int TPR = BK / 8;        // threads per staged row
  constexpr int RPR = 256 / TPR;     // rows per staging round
  constexpr int ROUNDS = 128 / RPR;  // rounds per matrix per K-step
  __shared__ __align__(16) unsigned short As[2][128 * BK];
  __shared__ __align__(16) unsigned short Bs[2][128 * BK];
  int tid = threadIdx.x;
  int l = tid & 63, wid = tid >> 6;
  int wr = wid >> 1, wc = wid & 1;

  // XCD-aware bijective swizzle: XCD k gets contiguous chunk of work ids
  int nwg = gridDim.x * gridDim.y;
  int flat = blockIdx.y * gridDim.x + blockIdx.x;
  int cpx = nwg >> 3;
  int work = (flat & 7) * cpx + (flat >> 3);
  int bx = work % gridDim.x, by = work / gridDim.x;
  int m0 = by * 128, n0 = bx * 128;
  int lr = l & 15, lk = (l >> 4) * 8;

  f32x4 acc[4][4];
#pragma unroll
  for (int m = 0; m < 4; m++)
#pragma unroll
    for (int n = 0; n < 4; n++) acc[m][n] = f32x4{0.f, 0.f, 0.f, 0.f};

  int sr = tid / TPR;          // staged row within round
  int sc8 = (tid % TPR) * 8;   // element col
  const unsigned short* Ag = A + (size_t)(m0 + sr) * K + sc8;
  const unsigned short* Bg = BT + (size_t)(n0 + sr) * K + sc8;

  auto stage = [&](int c, int k0) {
#pragma unroll
    for (int i = 0; i < ROUNDS; i++) {
      gl_lds16(Ag + (size_t)(i * RPR) * K + k0, &As[c][(sr + i * RPR) * BK + sc8]);
      gl_lds16(Bg + (size_t)(i * RPR) * K + k0, &Bs[c][(sr + i * RPR) * BK + sc8]);
    }
  };
  auto compute = [&](int c) {
#pragma unroll
    for (int ks = 0; ks < BK / 32; ks++) {
      bf16x8 af[4], bfr[4];
#pragma unroll
      for (int m = 0; m < 4; m++)
        af[m] = *reinterpret_cast<const bf16x8*>(&As[c][(wr * 64 + m * 16 + lr) * BK + ks * 32 + lk]);
#pragma unroll
      for (int n = 0; n < 4; n++)
        bfr[n] = *reinterpret_cast<const bf16x8*>(&Bs[c][(wc * 64 + n * 16 + lr) * BK + ks * 32 + lk]);
#pragma unroll
      for (int m = 0; m < 4; m++)
#pragma unroll
        for (int n = 0; n < 4; n++)
          acc[m][n] = __builtin_amdgcn_mfma_f32_16x16x32_bf16(af[m], bfr[n], acc[m][n], 0, 0, 0);
    }
  };

  const int nt = K / BK;
  stage(0, 0);
  __syncthreads();  // implicit vmcnt(0) drain -> buf0 staged
  int cur = 0;
  for (int t = 0; t < nt; ++t) {
    if (t + 1 < nt) stage(cur ^ 1, (t + 1) * BK);  // prefetch overlaps MFMA below
    compute(cur);
    __syncthreads();  // drains vmcnt (next buf staged) + all waves done reading cur
    cur ^= 1;
  }

  // epilogue: C/D layout col=lane&15, row=(lane>>4)*4+rr
#pragma unroll
  for (int m = 0; m < 4; m++) {
#pragma unroll
    for (int n = 0; n < 4; n++) {
      int gc = n0 + wc * 64 + n * 16 + lr;
      float bv = bias[gc];
#pragma unroll
      for (int rr = 0; rr < 4; rr++) {
        int gr = m0 + wr * 64 + m * 16 + (l >> 4) * 4 + rr;
        float v = acc[m][n][rr] + bv;
        if (EPI == 0) {
          outb[(size_t)gr * N + gc] = f2bf(v);
        } else if (EPI == 1) {
          resid[(size_t)gr * N + gc] += v;
        } else if (EPI == 2) {
          float gl = 0.5f * v * (1.0f + erff(v * 0.70710678118654752f));
          outb[(size_t)gr * N + gc] = f2bf(gl);
        } else {  // EPI 4: fused QKV. outb = Qb; Kb at +4M elems, VTb at +8M
          if (gc < 512) {
            outb[(size_t)gr * 512 + gc] = f2bf(v);
          } else if (gc < 1024) {
            (outb + 4194304)[(size_t)gr * 512 + (gc - 512)] = f2bf(v);
          } else {
            int c = gc - 1024;
            int h = c >> 6, dd = c & 63, bb = gr >> 9, ss = gr & 511;
            (outb + 8388608)[((size_t)((bb * H_ + h) * DK_ + dd)) * S_ + ss] = f2bf(v);
          }
        }
      }
    }
  }
}

// ---------------- attention: flash-style, LDS-staged K/V tiles ----------------
// grid (bh, qtile) bh-major. KV loop: 4 tiles of 128. Online softmax.
// K/V staged via global_load_lds with pre-swizzled SOURCE (rule 21).
// Bias via fragment-permuted bf16 table: 4x16B loads/tile (was 32 scalar 2B).
__global__ __launch_bounds__(256) void attn_kernel(const unsigned short* __restrict__ Q,
                                                   const unsigned short* __restrict__ K,
                                                   const unsigned short* __restrict__ VT,
                                                   const unsigned short* __restrict__ bias,
                                                   const unsigned char* __restrict__ mask,
                                                   unsigned short* __restrict__ O) {
  __shared__ __align__(16) unsigned short Ks[128 * 64];   // 16 KB [kvrow][dk] swz
  __shared__ __align__(16) unsigned short Vs[64 * 128];   // 16 KB [dk][kv] swz
  __shared__ __align__(16) unsigned short P[4][16 * 136]; // 17.4 KB wave-private
  int tid = threadIdx.x;
  int wid = tid >> 6, l = tid & 63;
  int bh = blockIdx.x;
  int b = bh >> 3, h = bh & 7;
  int q0 = blockIdx.y * 64 + wid * 16;
  int lr = l & 15;
  int lk = (l >> 4) * 8;
  int rb = (l >> 4) * 4;

  const unsigned short* qp = Q + (size_t)(b * S_ + q0 + lr) * D_ + h * DK_ + lk;
  bf16x8 aq0 = *reinterpret_cast<const bf16x8*>(qp);
  bf16x8 aq1 = *reinterpret_cast<const bf16x8*>(qp + 32);

  f32x4 ao[4];
#pragma unroll
  for (int n = 0; n < 4; n++) ao[n] = f32x4{0.f, 0.f, 0.f, 0.f};
  float m_[4] = {-3.0e38f, -3.0e38f, -3.0e38f, -3.0e38f};
  float l_[4] = {0.f, 0.f, 0.f, 0.f};

  for (int t = 0; t < 4; t++) {
    int s0 = t * 128;
    __syncthreads();
#pragma unroll
    for (int i = 0; i < 4; i++) {
      int c = (wid * 4 + i) * 64 + l;  // 0..1023
      int krow = c >> 3, kjs = c & 7, kj = kjs ^ (krow & 7);
      gl_lds16(K + (size_t)(b * S_ + s0 + krow) * D_ + h * DK_ + kj * 8, &Ks[c * 8]);
      int dk = c >> 4, vjs = c & 15, vj = vjs ^ (dk & 7);
      gl_lds16(VT + (size_t)(bh * DK_ + dk) * S_ + s0 + vj * 8, &Vs[c * 8]);
    }
    __syncthreads();

    // S-tile: 16 q-rows x 128 kv per wave
    f32x4 sc[8];
#pragma unroll
    for (int n = 0; n < 8; n++) sc[n] = f32x4{0.f, 0.f, 0.f, 0.f};
#pragma unroll
    for (int n = 0; n < 8; n++) {
      int r = n * 16 + lr;
      bf16x8 k0 = *reinterpret_cast<const bf16x8*>(&Ks[r * 64 + (((l >> 4)) ^ (r & 7)) * 8]);
      bf16x8 k1 = *reinterpret_cast<const bf16x8*>(&Ks[r * 64 + ((4 + (l >> 4)) ^ (r & 7)) * 8]);
      sc[n] = __builtin_amdgcn_mfma_f32_16x16x32_bf16(aq0, k0, sc[n], 0, 0, 0);
      sc[n] = __builtin_amdgcn_mfma_f32_16x16x32_bf16(aq1, k1, sc[n], 0, 0, 0);
    }

    // bias fragments: permuted layout [h][i][t][lr][n] -> one bf16x8 per row
    u16x8 bvv[4];
#pragma unroll
    for (int rr = 0; rr < 4; rr++)
      bvv[rr] = *reinterpret_cast<const u16x8*>(
          bias + (((size_t)h * S_ + (q0 + rb + rr)) * 4 + t) * 128 + lr * 8);

    float pmax[4] = {-3.0e38f, -3.0e38f, -3.0e38f, -3.0e38f};
#pragma unroll
    for (int n = 0; n < 8; n++) {
      int scn = n * 16 + lr;
      bool msk = mask[b * S_ + s0 + scn] != 0;
#pragma unroll
      for (int rr = 0; rr < 4; rr++) {
        float v = sc[n][rr] * 0.125f + bf2f(bvv[rr][n]);
        v = msk ? -1e9f : v;
        sc[n][rr] = v;
        pmax[rr] = fmaxf(pmax[rr], v);
      }
    }
#pragma unroll
    for (int rr = 0; rr < 4; rr++) {
#pragma unroll
      for (int mm = 1; mm < 16; mm <<= 1) pmax[rr] = fmaxf(pmax[rr], __shfl_xor(pmax[rr], mm));
    }
    float scl[4], psum[4];
#pragma unroll
    for (int rr = 0; rr < 4; rr++) {
      float mn = fmaxf(m_[rr], pmax[rr]);
      scl[rr] = __expf(m_[rr] - mn);
      m_[rr] = mn;
      psum[rr] = 0.f;
    }
#pragma unroll
    for (int n = 0; n < 8; n++) {
#pragma unroll
      for (int rr = 0; rr < 4; rr++) {
        float p = __expf(sc[n][rr] - m_[rr]);
        psum[rr] += p;
        P[wid][(rb + rr) * 136 + n * 16 + lr] = f2bf(p);
      }
    }
#pragma unroll
    for (int rr = 0; rr < 4; rr++) {
#pragma unroll
      for (int mm = 1; mm < 16; mm <<= 1) psum[rr] += __shfl_xor(psum[rr], mm);
      l_[rr] = l_[rr] * scl[rr] + psum[rr];
    }
#pragma unroll
    for (int n = 0; n < 4; n++)
#pragma unroll
      for (int rr = 0; rr < 4; rr++) ao[n][rr] *= scl[rr];

#pragma unroll
    for (int kk = 0; kk < 4; kk++) {
      bf16x8 pa = *reinterpret_cast<const bf16x8*>(&P[wid][lr * 136 + kk * 32 + lk]);
#pragma unroll
      for (int n = 0; n < 4; n++) {
        int dk = n * 16 + lr;
        bf16x8 vb = *reinterpret_cast<const bf16x8*>(&Vs[dk * 128 + ((kk * 4 + (l >> 4)) ^ (dk & 7)) * 8]);
        ao[n] = __builtin_amdgcn_mfma_f32_16x16x32_bf16(pa, vb, ao[n], 0, 0, 0);
      }
    }
  }

  float inv[4];
#pragma unroll
  for (int rr = 0; rr < 4; rr++) inv[rr] = 1.0f / l_[rr];
#pragma unroll
  for (int n = 0; n < 4; n++)
#pragma unroll
    for (int rr = 0; rr < 4; rr++)
      O[(size_t)(b * S_ + q0 + rb + rr) * D_ + h * DK_ + n * 16 + lr] = f2bf(ao[n][rr] * inv[rr]);
}

// ---------------- launch ----------------
extern "C" void kernel_launch(void* const* d_in, const int* in_sizes, int n_in,
                              void* d_out, int out_size, void* d_ws, size_t ws_size,
                              hipStream_t stream) {
  const float* x = (const float*)d_in[0];
  const float* coords = (const float*)d_in[1];
  const float* cls_pe = (const float*)d_in[2];
  const float* bias_emb = (const float*)d_in[3];
  const float* attn_w = (const float*)d_in[4];
  const float* attn_b = (const float*)d_in[5];
  const float* ff_w1 = (const float*)d_in[6];
  const float* ff_b1 = (const float*)d_in[7];
  const float* ff_w2 = (const float*)d_in[8];
  const float* ff_b2 = (const float*)d_in[9];
  const float* ln_g = (const float*)d_in[10];
  const float* ln_b = (const float*)d_in[11];
  const float* norm_g = (const float*)d_in[12];
  const float* norm_b = (const float*)d_in[13];
  const float* norm2_g = (const float*)d_in[14];
  const float* norm2_b = (const float*)d_in[15];
  const unsigned char* mask = (const unsigned char*)d_in[16];

  char* ws = (char*)d_ws;
  float* xf = (float*)(ws + 0);                                   // 16 MB
  unsigned short* biasbuf = (unsigned short*)(ws + 16777216);     // 4 MB bf16 permuted
  unsigned short* wattnT = (unsigned short*)(ws + 25165824);      // 12 MB
  unsigned short* wff1T = (unsigned short*)(ws + 37748736);       // 12 MB
  unsigned short* wff2T = (unsigned short*)(ws + 50331648);       // 12 MB
  unsigned short* lnbuf = (unsigned short*)(ws + 62914560);       // 8 MB
  unsigned short* Qb = (unsigned short*)(ws + 71303168);          // 8 MB
  unsigned short* Kb = (unsigned short*)(ws + 79691776);          // 8 MB  (= Qb + 4194304 elems)
  unsigned short* VTb = (unsigned short*)(ws + 88080384);         // 8 MB  (= Qb + 8388608 elems)
  unsigned short* Ob = (unsigned short*)(ws + 96468992);          // 8 MB
  unsigned short* H1b = Qb;  // 32 MB FF hidden aliases Q/K/VT/O (disjoint lifetimes)

  const int M = B_ * S_;

  pe_add_kernel<<<(B_ * S_ * D_) / 256, 256, 0, stream>>>(x, coords, cls_pe, xf);
  bias_kernel<<<(S_ * S_) / 256, 256, 0, stream>>>(coords, bias_emb, biasbuf);
  transpose_cvt<<<dim3(16, 16, 24), 256, 0, stream>>>(attn_w, wattnT, 512, 512);
  transpose_cvt<<<dim3(64, 16, 6), 256, 0, stream>>>(ff_w1, wff1T, 512, 2048);
  transpose_cvt<<<dim3(16, 64, 6), 256, 0, stream>>>(ff_w2, wff2T, 2048, 512);

  for (int i = 0; i < NL_; i++) {
    ln_kernel<0><<<M / 4, 256, 0, stream>>>(xf, ln_g + (i * 2 + 0) * D_, ln_b + (i * 2 + 0) * D_, lnbuf);
    // QKV: 768 blocks (3/CU) -> BK=32 keeps TLP
    gemm_bt<4, 32><<<dim3(12, 64), 256, 0, stream>>>(lnbuf, wattnT + (size_t)(i * 4 + 0) * D_ * D_,
                                                     attn_b + (i * 4 + 0) * D_, Qb, nullptr, M, 1536, D_);
    attn_kernel<<<dim3(B_ * H_, 8), 256, 0, stream>>>(Qb, Kb, VTb, biasbuf, mask, Ob);
    // O-proj: 256 blocks (1/CU) -> BK=64 deep pipeline
    gemm_bt<1, 64><<<dim3(4, 64), 256, 0, stream>>>(Ob, wattnT + (size_t)(i * 4 + 3) * D_ * D_,
                                                    attn_b + (i * 4 + 3) * D_, nullptr, xf, M, D_, D_);
    ln_kernel<0><<<M / 4, 256, 0, stream>>>(xf, ln_g + (i * 2 + 1) * D_, ln_b + (i * 2 + 1) * D_, lnbuf);
    // FF1: 1024 blocks (4/CU) -> BK=32 keeps TLP
    gemm_bt<2, 32><<<dim3(16, 64), 256, 0, stream>>>(lnbuf, wff1T + (size_t)i * DFF_ * D_,
                                                     ff_b1 + i * DFF_, H1b, nullptr, M, DFF_, D_);
    // FF2: 256 blocks (1/CU) -> BK=64 deep pipeline
    gemm_bt<1, 64><<<dim3(4, 64), 256, 0, stream>>>(H1b, wff2T + (size_t)i * D_ * DFF_,
                                                    ff_b2 + i * D_, nullptr, xf, M, D_, DFF_);
    if (i == 2) ln_kernel<1><<<M / 4, 256, 0, stream>>>(xf, norm2_g, norm2_b, xf);
  }
  ln_kernel<1><<<M / 4, 256, 0, stream>>>(xf, norm_g, norm_b, (float*)d_out);
}

// Round 14
// 1247.663 us; speedup vs baseline: 1.4604x; 1.0703x over previous
//
#include <hip/hip_runtime.h>
#include <cstdint>
#include <cstddef>

#define B_ 16
#define S_ 512
#define D_ 512
#define H_ 8
#define DK_ 64
#define NL_ 6
#define DFF_ 2048

typedef float f32x4 __attribute__((ext_vector_type(4)));
typedef __bf16 bf16x8 __attribute__((ext_vector_type(8)));
typedef unsigned short u16x8 __attribute__((ext_vector_type(8)));

__device__ __forceinline__ unsigned short f2bf(float f) {
  unsigned u = __builtin_bit_cast(unsigned, f);
  unsigned r = (u + 0x7FFFu + ((u >> 16) & 1u)) >> 16;  // RNE
  return (unsigned short)r;
}
__device__ __forceinline__ float bf2f(unsigned short v) {
  unsigned u = ((unsigned)v) << 16;
  return __builtin_bit_cast(float, u);
}

// async global->LDS, 16B per lane (m97 staging lever)
__device__ __forceinline__ void gl_lds16(const unsigned short* g, unsigned short* l) {
  __builtin_amdgcn_global_load_lds(
      (const __attribute__((address_space(1))) unsigned int*)g,
      (__attribute__((address_space(3))) unsigned int*)l, 16, 0, 0);
}

// ---------------- positional encoding add: xo = x + pe2d ----------------
__global__ __launch_bounds__(256) void pe_add_kernel(const float* __restrict__ x,
                                                     const float* __restrict__ coords,
                                                     const float* __restrict__ cls_pe,
                                                     float* __restrict__ xo) {
  int idx = blockIdx.x * 256 + threadIdx.x;
  int d = idx & (D_ - 1);
  int s = (idx >> 9) & (S_ - 1);
  float pe;
  if (s == 0) {
    pe = cls_pe[d];
  } else {
    float c = coords[(s - 1) * 2 + (d >= 256 ? 1 : 0)];
    int dd = d & 255;
    int t = dd >> 1;
    float ang = c * expf((float)t * -0.07195578415606394f);
    pe = (dd & 1) ? cosf(ang) : sinf(ang);
  }
  xo[idx] = x[idx] + pe;
}

// ---------------- rel-pos bias table, bf16, fragment-permuted ----------------
// layout [h][i][t(4)][lr(16)][n(8)]: attn thread (lr) reads bf16x8 per (i, t)
__global__ __launch_bounds__(256) void bias_kernel(const float* __restrict__ coords,
                                                   const float* __restrict__ emb,
                                                   unsigned short* __restrict__ bias) {
  int idx = blockIdx.x * 256 + threadIdx.x;  // i*S + j
  int j = idx & (S_ - 1), i = idx >> 9;
  unsigned short v[H_];
  if (i == 0 || j == 0) {
#pragma unroll
    for (int h = 0; h < H_; h++) v[h] = 0;
  } else {
    float dx = coords[(i - 1) * 2] - coords[(j - 1) * 2];
    float dy = coords[(i - 1) * 2 + 1] - coords[(j - 1) * 2 + 1];
    float dist = sqrtf(dx * dx + dy * dy);
    float t = fminf(dist / 10.0f, 1.0f) * 31.0f;
    int bkt = (int)t;
#pragma unroll
    for (int h = 0; h < H_; h++) v[h] = f2bf(emb[bkt * H_ + h]);
  }
  int t = j >> 7, w = j & 127, plr = w & 15, pn = w >> 4;
#pragma unroll
  for (int h = 0; h < H_; h++)
    bias[(((size_t)h * S_ + i) * 4 + t) * 128 + plr * 8 + pn] = v[h];
}

// ---------------- transpose + fp32->bf16: dst[c][r] = src[r][c] ----------------
__global__ __launch_bounds__(256) void transpose_cvt(const float* __restrict__ src,
                                                     unsigned short* __restrict__ dst,
                                                     int R, int C) {
  src += (size_t)blockIdx.z * R * C;
  dst += (size_t)blockIdx.z * R * C;
  __shared__ float tile[32][33];
  int tx = threadIdx.x & 31, ty = threadIdx.x >> 5;  // 32 x 8
  int c0 = blockIdx.x * 32, r0 = blockIdx.y * 32;
#pragma unroll
  for (int i = 0; i < 32; i += 8)
    tile[ty + i][tx] = src[(size_t)(r0 + ty + i) * C + c0 + tx];
  __syncthreads();
#pragma unroll
  for (int i = 0; i < 32; i += 8)
    dst[(size_t)(c0 + ty + i) * R + r0 + tx] = f2bf(tile[tx][ty + i]);
}

// ---------------- LayerNorm: one wave per row of 512 ----------------
template <int OUTMODE>  // 0: bf16 out; 1: fp32 out (in-place ok)
__global__ __launch_bounds__(256) void ln_kernel(const float* __restrict__ x,
                                                 const float* __restrict__ g,
                                                 const float* __restrict__ be,
                                                 void* __restrict__ out) {
  int wid = threadIdx.x >> 6, l = threadIdx.x & 63;
  size_t row = (size_t)blockIdx.x * 4 + wid;
  const float4* xr = reinterpret_cast<const float4*>(x + row * D_);
  float4 a = xr[l * 2], c = xr[l * 2 + 1];
  float s = a.x + a.y + a.z + a.w + c.x + c.y + c.z + c.w;
  float sq = a.x * a.x + a.y * a.y + a.z * a.z + a.w * a.w +
             c.x * c.x + c.y * c.y + c.z * c.z + c.w * c.w;
#pragma unroll
  for (int m = 1; m < 64; m <<= 1) {
    s += __shfl_xor(s, m);
    sq += __shfl_xor(sq, m);
  }
  float mean = s * (1.0f / D_);
  float var = sq * (1.0f / D_) - mean * mean;
  float rstd = rsqrtf(var + 1e-5f);
  const float4* gp = reinterpret_cast<const float4*>(g);
  const float4* bp = reinterpret_cast<const float4*>(be);
  float4 g0 = gp[l * 2], g1 = gp[l * 2 + 1];
  float4 b0 = bp[l * 2], b1 = bp[l * 2 + 1];
  float y[8];
  y[0] = (a.x - mean) * rstd * g0.x + b0.x;
  y[1] = (a.y - mean) * rstd * g0.y + b0.y;
  y[2] = (a.z - mean) * rstd * g0.z + b0.z;
  y[3] = (a.w - mean) * rstd * g0.w + b0.w;
  y[4] = (c.x - mean) * rstd * g1.x + b1.x;
  y[5] = (c.y - mean) * rstd * g1.y + b1.y;
  y[6] = (c.z - mean) * rstd * g1.z + b1.z;
  y[7] = (c.w - mean) * rstd * g1.w + b1.w;
  if (OUTMODE == 0) {
    u16x8 o;
#pragma unroll
    for (int j = 0; j < 8; j++) o[j] = f2bf(y[j]);
    *reinterpret_cast<u16x8*>((unsigned short*)out + row * D_ + l * 8) = o;
  } else {
    float4 o0 = {y[0], y[1], y[2], y[3]};
    float4 o1 = {y[4], y[5], y[6], y[7]};
    float4* op = reinterpret_cast<float4*>((float*)out + row * D_ + l * 8);
    op[0] = o0;
    op[1] = o1;
  }
}

// ---------------- GEMM 128x128: R12 champion (QKV / FF1) ----------------
// 4 waves (2x2), 2-phase dbuf, BK templated. T1 bijective XCD swizzle.
template <int EPI, int BK>
__global__ __launch_bounds__(256) void gemm_bt(const unsigned short* __restrict__ A,
                                               const unsigned short* __restrict__ BT,
                                               const float* __restrict__ bias,
                                               unsigned short* __restrict__ outb,
                                               float* __restrict__ resid,
                                               int M, int N, int K) {
  constexpr int TPR = BK / 8;
  constexpr int RPR = 256 / TPR;
  constexpr int ROUNDS = 128 / RPR;
  __shared__ __align__(16) unsigned short As[2][128 * BK];
  __shared__ __align__(16) unsigned short Bs[2][128 * BK];
  int tid = threadIdx.x;
  int l = tid & 63, wid = tid >> 6;
  int wr = wid >> 1, wc = wid & 1;

  int nwg = gridDim.x * gridDim.y;
  int flat = blockIdx.y * gridDim.x + blockIdx.x;
  int cpx = nwg >> 3;
  int work = (flat & 7) * cpx + (flat >> 3);
  int bx = work % gridDim.x, by = work / gridDim.x;
  int m0 = by * 128, n0 = bx * 128;
  int lr = l & 15, lk = (l >> 4) * 8;

  f32x4 acc[4][4];
#pragma unroll
  for (int m = 0; m < 4; m++)
#pragma unroll
    for (int n = 0; n < 4; n++) acc[m][n] = f32x4{0.f, 0.f, 0.f, 0.f};

  int sr = tid / TPR;
  int sc8 = (tid % TPR) * 8;
  const unsigned short* Ag = A + (size_t)(m0 + sr) * K + sc8;
  const unsigned short* Bg = BT + (size_t)(n0 + sr) * K + sc8;

  auto stage = [&](int c, int k0) {
#pragma unroll
    for (int i = 0; i < ROUNDS; i++) {
      gl_lds16(Ag + (size_t)(i * RPR) * K + k0, &As[c][(sr + i * RPR) * BK + sc8]);
      gl_lds16(Bg + (size_t)(i * RPR) * K + k0, &Bs[c][(sr + i * RPR) * BK + sc8]);
    }
  };
  auto compute = [&](int c) {
#pragma unroll
    for (int ks = 0; ks < BK / 32; ks++) {
      bf16x8 af[4], bfr[4];
#pragma unroll
      for (int m = 0; m < 4; m++)
        af[m] = *reinterpret_cast<const bf16x8*>(&As[c][(wr * 64 + m * 16 + lr) * BK + ks * 32 + lk]);
#pragma unroll
      for (int n = 0; n < 4; n++)
        bfr[n] = *reinterpret_cast<const bf16x8*>(&Bs[c][(wc * 64 + n * 16 + lr) * BK + ks * 32 + lk]);
#pragma unroll
      for (int m = 0; m < 4; m++)
#pragma unroll
        for (int n = 0; n < 4; n++)
          acc[m][n] = __builtin_amdgcn_mfma_f32_16x16x32_bf16(af[m], bfr[n], acc[m][n], 0, 0, 0);
    }
  };

  const int nt = K / BK;
  stage(0, 0);
  __syncthreads();
  int cur = 0;
  for (int t = 0; t < nt; ++t) {
    if (t + 1 < nt) stage(cur ^ 1, (t + 1) * BK);
    compute(cur);
    __syncthreads();
    cur ^= 1;
  }

#pragma unroll
  for (int m = 0; m < 4; m++) {
#pragma unroll
    for (int n = 0; n < 4; n++) {
      int gc = n0 + wc * 64 + n * 16 + lr;
      float bv = bias[gc];
#pragma unroll
      for (int rr = 0; rr < 4; rr++) {
        int gr = m0 + wr * 64 + m * 16 + (l >> 4) * 4 + rr;
        float v = acc[m][n][rr] + bv;
        if (EPI == 0) {
          outb[(size_t)gr * N + gc] = f2bf(v);
        } else if (EPI == 1) {
          resid[(size_t)gr * N + gc] += v;
        } else if (EPI == 2) {
          float gl = 0.5f * v * (1.0f + erff(v * 0.70710678118654752f));
          outb[(size_t)gr * N + gc] = f2bf(gl);
        } else {  // EPI 4: fused QKV. outb = Qb; Kb at +4M elems, VTb at +8M
          if (gc < 512) {
            outb[(size_t)gr * 512 + gc] = f2bf(v);
          } else if (gc < 1024) {
            (outb + 4194304)[(size_t)gr * 512 + (gc - 512)] = f2bf(v);
          } else {
            int c = gc - 1024;
            int h = c >> 6, dd = c & 63, bb = gr >> 9, ss = gr & 511;
            (outb + 8388608)[((size_t)((bb * H_ + h) * DK_ + dd)) * S_ + ss] = f2bf(v);
          }
        }
      }
    }
  }
}

// ---------------- GEMM 128x64 tile: for 256-block shapes (O-proj, FF2) --------
// Grid doubles to 512 blocks = 2 blocks/CU: cross-block TLP hides the barrier
// drain (m114) ON TOP of the dbuf pipeline. 4 waves (2x2), wave tile 64x32.
// LDS 48KB/block -> 96KB/CU. Same 2-phase loop as gemm_bt (proven).
template <int EPI>
__global__ __launch_bounds__(256) void gemm_n64(const unsigned short* __restrict__ A,
                                                const unsigned short* __restrict__ BT,
                                                const float* __restrict__ bias,
                                                unsigned short* __restrict__ outb,
                                                float* __restrict__ resid,
                                                int M, int N, int K) {
  constexpr int BK = 64;
  __shared__ __align__(16) unsigned short As[2][128 * BK];  // 16 KB x2
  __shared__ __align__(16) unsigned short Bs[2][64 * BK];   // 8 KB x2
  int tid = threadIdx.x;
  int l = tid & 63, wid = tid >> 6;
  int wr = wid >> 1, wc = wid & 1;  // wave tile 64(M) x 32(N)

  int nwg = gridDim.x * gridDim.y;
  int flat = blockIdx.y * gridDim.x + blockIdx.x;
  int cpx = nwg >> 3;
  int work = (flat & 7) * cpx + (flat >> 3);
  int bx = work % gridDim.x, by = work / gridDim.x;
  int m0 = by * 128, n0 = bx * 64;
  int lr = l & 15, lk = (l >> 4) * 8;

  f32x4 acc[4][2];
#pragma unroll
  for (int m = 0; m < 4; m++)
#pragma unroll
    for (int n = 0; n < 2; n++) acc[m][n] = f32x4{0.f, 0.f, 0.f, 0.f};

  int sr = tid >> 3;         // 0..31
  int sc8 = (tid & 7) * 8;   // 0..56
  const unsigned short* Ag = A + (size_t)(m0 + sr) * K + sc8;
  const unsigned short* Bg = BT + (size_t)(n0 + sr) * K + sc8;

  auto stage = [&](int c, int k0) {
#pragma unroll
    for (int i = 0; i < 4; i++)
      gl_lds16(Ag + (size_t)(i * 32) * K + k0, &As[c][(sr + i * 32) * BK + sc8]);
#pragma unroll
    for (int i = 0; i < 2; i++)
      gl_lds16(Bg + (size_t)(i * 32) * K + k0, &Bs[c][(sr + i * 32) * BK + sc8]);
  };
  auto compute = [&](int c) {
#pragma unroll
    for (int ks = 0; ks < 2; ks++) {
      bf16x8 af[4], bfr[2];
#pragma unroll
      for (int m = 0; m < 4; m++)
        af[m] = *reinterpret_cast<const bf16x8*>(&As[c][(wr * 64 + m * 16 + lr) * BK + ks * 32 + lk]);
#pragma unroll
      for (int n = 0; n < 2; n++)
        bfr[n] = *reinterpret_cast<const bf16x8*>(&Bs[c][(wc * 32 + n * 16 + lr) * BK + ks * 32 + lk]);
#pragma unroll
      for (int m = 0; m < 4; m++)
#pragma unroll
        for (int n = 0; n < 2; n++)
          acc[m][n] = __builtin_amdgcn_mfma_f32_16x16x32_bf16(af[m], bfr[n], acc[m][n], 0, 0, 0);
    }
  };

  const int nt = K / BK;
  stage(0, 0);
  __syncthreads();
  int cur = 0;
  for (int t = 0; t < nt; ++t) {
    if (t + 1 < nt) stage(cur ^ 1, (t + 1) * BK);
    compute(cur);
    __syncthreads();
    cur ^= 1;
  }

#pragma unroll
  for (int m = 0; m < 4; m++) {
#pragma unroll
    for (int n = 0; n < 2; n++) {
      int gc = n0 + wc * 32 + n * 16 + lr;
      float bv = bias[gc];
#pragma unroll
      for (int rr = 0; rr < 4; rr++) {
        int gr = m0 + wr * 64 + m * 16 + (l >> 4) * 4 + rr;
        float v = acc[m][n][rr] + bv;
        if (EPI == 1) {
          resid[(size_t)gr * N + gc] += v;
        } else {
          outb[(size_t)gr * N + gc] = f2bf(v);
        }
      }
    }
  }
}

// ---------------- attention: flash-style, LDS-staged K/V tiles ----------------
__global__ __launch_bounds__(256) void attn_kernel(const unsigned short* __restrict__ Q,
                                                   const unsigned short* __restrict__ K,
                                                   const unsigned short* __restrict__ VT,
                                                   const unsigned short* __restrict__ bias,
                                                   const unsigned char* __restrict__ mask,
                                                   unsigned short* __restrict__ O) {
  __shared__ __align__(16) unsigned short Ks[128 * 64];   // 16 KB [kvrow][dk] swz
  __shared__ __align__(16) unsigned short Vs[64 * 128];   // 16 KB [dk][kv] swz
  __shared__ __align__(16) unsigned short P[4][16 * 136]; // 17.4 KB wave-private
  int tid = threadIdx.x;
  int wid = tid >> 6, l = tid & 63;
  int bh = blockIdx.x;
  int b = bh >> 3, h = bh & 7;
  int q0 = blockIdx.y * 64 + wid * 16;
  int lr = l & 15;
  int lk = (l >> 4) * 8;
  int rb = (l >> 4) * 4;

  const unsigned short* qp = Q + (size_t)(b * S_ + q0 + lr) * D_ + h * DK_ + lk;
  bf16x8 aq0 = *reinterpret_cast<const bf16x8*>(qp);
  bf16x8 aq1 = *reinterpret_cast<const bf16x8*>(qp + 32);

  f32x4 ao[4];
#pragma unroll
  for (int n = 0; n < 4; n++) ao[n] = f32x4{0.f, 0.f, 0.f, 0.f};
  float m_[4] = {-3.0e38f, -3.0e38f, -3.0e38f, -3.0e38f};
  float l_[4] = {0.f, 0.f, 0.f, 0.f};

  for (int t = 0; t < 4; t++) {
    int s0 = t * 128;
    __syncthreads();
#pragma unroll
    for (int i = 0; i < 4; i++) {
      int c = (wid * 4 + i) * 64 + l;  // 0..1023
      int krow = c >> 3, kjs = c & 7, kj = kjs ^ (krow & 7);
      gl_lds16(K + (size_t)(b * S_ + s0 + krow) * D_ + h * DK_ + kj * 8, &Ks[c * 8]);
      int dk = c >> 4, vjs = c & 15, vj = vjs ^ (dk & 7);
      gl_lds16(VT + (size_t)(bh * DK_ + dk) * S_ + s0 + vj * 8, &Vs[c * 8]);
    }
    __syncthreads();

    // S-tile: 16 q-rows x 128 kv per wave
    f32x4 sc[8];
#pragma unroll
    for (int n = 0; n < 8; n++) sc[n] = f32x4{0.f, 0.f, 0.f, 0.f};
#pragma unroll
    for (int n = 0; n < 8; n++) {
      int r = n * 16 + lr;
      bf16x8 k0 = *reinterpret_cast<const bf16x8*>(&Ks[r * 64 + (((l >> 4)) ^ (r & 7)) * 8]);
      bf16x8 k1 = *reinterpret_cast<const bf16x8*>(&Ks[r * 64 + ((4 + (l >> 4)) ^ (r & 7)) * 8]);
      sc[n] = __builtin_amdgcn_mfma_f32_16x16x32_bf16(aq0, k0, sc[n], 0, 0, 0);
      sc[n] = __builtin_amdgcn_mfma_f32_16x16x32_bf16(aq1, k1, sc[n], 0, 0, 0);
    }

    // bias fragments: permuted layout [h][i][t][lr][n] -> one bf16x8 per row
    u16x8 bvv[4];
#pragma unroll
    for (int rr = 0; rr < 4; rr++)
      bvv[rr] = *reinterpret_cast<const u16x8*>(
          bias + (((size_t)h * S_ + (q0 + rb + rr)) * 4 + t) * 128 + lr * 8);

    float pmax[4] = {-3.0e38f, -3.0e38f, -3.0e38f, -3.0e38f};
#pragma unroll
    for (int n = 0; n < 8; n++) {
      int scn = n * 16 + lr;
      bool msk = mask[b * S_ + s0 + scn] != 0;
#pragma unroll
      for (int rr = 0; rr < 4; rr++) {
        float v = sc[n][rr] * 0.125f + bf2f(bvv[rr][n]);
        v = msk ? -1e9f : v;
        sc[n][rr] = v;
        pmax[rr] = fmaxf(pmax[rr], v);
      }
    }
#pragma unroll
    for (int rr = 0; rr < 4; rr++) {
#pragma unroll
      for (int mm = 1; mm < 16; mm <<= 1) pmax[rr] = fmaxf(pmax[rr], __shfl_xor(pmax[rr], mm));
    }
    float scl[4], psum[4];
#pragma unroll
    for (int rr = 0; rr < 4; rr++) {
      float mn = fmaxf(m_[rr], pmax[rr]);
      scl[rr] = __expf(m_[rr] - mn);
      m_[rr] = mn;
      psum[rr] = 0.f;
    }
#pragma unroll
    for (int n = 0; n < 8; n++) {
#pragma unroll
      for (int rr = 0; rr < 4; rr++) {
        float p = __expf(sc[n][rr] - m_[rr]);
        psum[rr] += p;
        P[wid][(rb + rr) * 136 + n * 16 + lr] = f2bf(p);
      }
    }
#pragma unroll
    for (int rr = 0; rr < 4; rr++) {
#pragma unroll
      for (int mm = 1; mm < 16; mm <<= 1) psum[rr] += __shfl_xor(psum[rr], mm);
      l_[rr] = l_[rr] * scl[rr] + psum[rr];
    }
#pragma unroll
    for (int n = 0; n < 4; n++)
#pragma unroll
      for (int rr = 0; rr < 4; rr++) ao[n][rr] *= scl[rr];

#pragma unroll
    for (int kk = 0; kk < 4; kk++) {
      bf16x8 pa = *reinterpret_cast<const bf16x8*>(&P[wid][lr * 136 + kk * 32 + lk]);
#pragma unroll
      for (int n = 0; n < 4; n++) {
        int dk = n * 16 + lr;
        bf16x8 vb = *reinterpret_cast<const bf16x8*>(&Vs[dk * 128 + ((kk * 4 + (l >> 4)) ^ (dk & 7)) * 8]);
        ao[n] = __builtin_amdgcn_mfma_f32_16x16x32_bf16(pa, vb, ao[n], 0, 0, 0);
      }
    }
  }

  float inv[4];
#pragma unroll
  for (int rr = 0; rr < 4; rr++) inv[rr] = 1.0f / l_[rr];
#pragma unroll
  for (int n = 0; n < 4; n++)
#pragma unroll
    for (int rr = 0; rr < 4; rr++)
      O[(size_t)(b * S_ + q0 + rb + rr) * D_ + h * DK_ + n * 16 + lr] = f2bf(ao[n][rr] * inv[rr]);
}

// ---------------- launch ----------------
extern "C" void kernel_launch(void* const* d_in, const int* in_sizes, int n_in,
                              void* d_out, int out_size, void* d_ws, size_t ws_size,
                              hipStream_t stream) {
  const float* x = (const float*)d_in[0];
  const float* coords = (const float*)d_in[1];
  const float* cls_pe = (const float*)d_in[2];
  const float* bias_emb = (const float*)d_in[3];
  const float* attn_w = (const float*)d_in[4];
  const float* attn_b = (const float*)d_in[5];
  const float* ff_w1 = (const float*)d_in[6];
  const float* ff_b1 = (const float*)d_in[7];
  const float* ff_w2 = (const float*)d_in[8];
  const float* ff_b2 = (const float*)d_in[9];
  const float* ln_g = (const float*)d_in[10];
  const float* ln_b = (const float*)d_in[11];
  const float* norm_g = (const float*)d_in[12];
  const float* norm_b = (const float*)d_in[13];
  const float* norm2_g = (const float*)d_in[14];
  const float* norm2_b = (const float*)d_in[15];
  const unsigned char* mask = (const unsigned char*)d_in[16];

  char* ws = (char*)d_ws;
  float* xf = (float*)(ws + 0);                                   // 16 MB
  unsigned short* biasbuf = (unsigned short*)(ws + 16777216);     // 4 MB bf16 permuted
  unsigned short* wattnT = (unsigned short*)(ws + 25165824);      // 12 MB
  unsigned short* wff1T = (unsigned short*)(ws + 37748736);       // 12 MB
  unsigned short* wff2T = (unsigned short*)(ws + 50331648);       // 12 MB
  unsigned short* lnbuf = (unsigned short*)(ws + 62914560);       // 8 MB
  unsigned short* Qb = (unsigned short*)(ws + 71303168);          // 8 MB
  unsigned short* Kb = (unsigned short*)(ws + 79691776);          // 8 MB  (= Qb + 4194304 elems)
  unsigned short* VTb = (unsigned short*)(ws + 88080384);         // 8 MB  (= Qb + 8388608 elems)
  unsigned short* Ob = (unsigned short*)(ws + 96468992);          // 8 MB
  unsigned short* H1b = Qb;  // 32 MB FF hidden aliases Q/K/VT/O (disjoint lifetimes)

  const int M = B_ * S_;

  pe_add_kernel<<<(B_ * S_ * D_) / 256, 256, 0, stream>>>(x, coords, cls_pe, xf);
  bias_kernel<<<(S_ * S_) / 256, 256, 0, stream>>>(coords, bias_emb, biasbuf);
  transpose_cvt<<<dim3(16, 16, 24), 256, 0, stream>>>(attn_w, wattnT, 512, 512);
  transpose_cvt<<<dim3(64, 16, 6), 256, 0, stream>>>(ff_w1, wff1T, 512, 2048);
  transpose_cvt<<<dim3(16, 64, 6), 256, 0, stream>>>(ff_w2, wff2T, 2048, 512);

  for (int i = 0; i < NL_; i++) {
    ln_kernel<0><<<M / 4, 256, 0, stream>>>(xf, ln_g + (i * 2 + 0) * D_, ln_b + (i * 2 + 0) * D_, lnbuf);
    // QKV: 768 blocks (3/CU) -> BK=32 keeps TLP
    gemm_bt<4, 32><<<dim3(12, 64), 256, 0, stream>>>(lnbuf, wattnT + (size_t)(i * 4 + 0) * D_ * D_,
                                                     attn_b + (i * 4 + 0) * D_, Qb, nullptr, M, 1536, D_);
    attn_kernel<<<dim3(B_ * H_, 8), 256, 0, stream>>>(Qb, Kb, VTb, biasbuf, mask, Ob);
    // O-proj: 128x64 tile -> 512 blocks (2/CU) + BK=64 dbuf
    gemm_n64<1><<<dim3(8, 64), 256, 0, stream>>>(Ob, wattnT + (size_t)(i * 4 + 3) * D_ * D_,
                                                 attn_b + (i * 4 + 3) * D_, nullptr, xf, M, D_, D_);
    ln_kernel<0><<<M / 4, 256, 0, stream>>>(xf, ln_g + (i * 2 + 1) * D_, ln_b + (i * 2 + 1) * D_, lnbuf);
    // FF1: 1024 blocks (4/CU) -> BK=32 keeps TLP
    gemm_bt<2, 32><<<dim3(16, 64), 256, 0, stream>>>(lnbuf, wff1T + (size_t)i * DFF_ * D_,
                                                     ff_b1 + i * DFF_, H1b, nullptr, M, DFF_, D_);
    // FF2: 128x64 tile -> 512 blocks (2/CU) + BK=64 dbuf
    gemm_n64<1><<<dim3(8, 64), 256, 0, stream>>>(H1b, wff2T + (size_t)i * D_ * DFF_,
                                                 ff_b2 + i * D_, nullptr, xf, M, D_, DFF_);
    if (i == 2) ln_kernel<1><<<M / 4, 256, 0, stream>>>(xf, norm2_g, norm2_b, xf);
  }
  ln_kernel<1><<<M / 4, 256, 0, stream>>>(xf, norm_g, norm_b, (float*)d_out);
}